// Round 12
// baseline (97.605 us; speedup 1.0000x reference)
//
#include <hip/hip_runtime.h>
#include <hip/hip_bf16.h>

#define B_    128
#define H_    256
#define WI_   256
#define CIN   8
#define COUT  8
#define SS    32
#define RST   (WI_*CIN)     // 2048 f32 per input row
#define OST   (WI_*COUT)    // 2048 f32 per output row

typedef __attribute__((ext_vector_type(8))) short bh8;   // 8 bf16 (MFMA A/B frag)
typedef __attribute__((ext_vector_type(4))) float f4;    // MFMA C/D frag

static __device__ __forceinline__ unsigned short f2bf(float f) {
    union { __hip_bfloat16 h; unsigned short u; } c;
    c.h = __float2bfloat16(f);
    return c.u;
}

static __device__ __forceinline__ bh8 pack_mask(float4 lo, float4 hi, unsigned m) {
    union { bh8 v; unsigned short u[8]; unsigned w[4]; } r;
    r.u[0]=f2bf(lo.x); r.u[1]=f2bf(lo.y); r.u[2]=f2bf(lo.z); r.u[3]=f2bf(lo.w);
    r.u[4]=f2bf(hi.x); r.u[5]=f2bf(hi.y); r.u[6]=f2bf(hi.z); r.u[7]=f2bf(hi.w);
    r.w[0]&=m; r.w[1]&=m; r.w[2]&=m; r.w[3]&=m;
    return r.v;
}

// wave = TWO adjacent 16-column subtiles (32 cols) marching down SS=32 rows.
// MFMA: D = Wfrag(A, M=cout) x Xfrag(B, N=pixel) + C  (per subtile)
// Depth-2 prefetch, 3 rotating named buffer-pairs; NT stores.
// SS=32 -> 2048 blocks = 8/CU resident: 2x outstanding loads, finer drain.
__global__ __launch_bounds__(256, 2)
void conv_mfma_kernel(const float* __restrict__ X,
                      const float* __restrict__ Wt,
                      const float* __restrict__ bias,
                      const float* __restrict__ Werr,
                      const float* __restrict__ Berr,
                      float* __restrict__ out)
{
    __shared__ float wlds[576];           // noisy weights, transposed [khkw][cout][cin]
    const int tid = threadIdx.x;
    const int b   = blockIdx.z;
    const int rs  = blockIdx.y * SS;

    {
        const float* we = Werr + (size_t)b * 576;
        for (int i = tid; i < 576; i += 256) {
            const int khkw = i >> 6, ci = (i >> 3) & 7, co = i & 7;
            wlds[(khkw * 8 + co) * 8 + ci] = Wt[i] * we[i];
        }
    }
    __syncthreads();

    const int lane = tid & 63, wid = tid >> 6;
    const int w0 = (blockIdx.x * 4 + wid) * 32;   // 32 cols per wave
    const int p  = lane & 15;
    const int g  = lane >> 4;

    // ---- weight fragments (shared by both subtiles) ----
    bh8 Wf0, Wf1, Wf2;
    {
        const float4 z4 = make_float4(0.f, 0.f, 0.f, 0.f);
        #pragma unroll
        for (int kh = 0; kh < 3; ++kh) {
            float4 lo = z4, hi = z4;
            if (p < 8 && g < 3) {
                const float* ptr = &wlds[((kh * 3 + g) * 8 + p) * 8];
                lo = *(const float4*)ptr;
                hi = *(const float4*)(ptr + 4);
            }
            const bh8 f = pack_mask(lo, hi, 0xffffffffu);
            if (kh == 0) Wf0 = f; else if (kh == 1) Wf1 = f; else Wf2 = f;
        }
    }

    f4 biasF = {0.f, 0.f, 0.f, 0.f};
    if (g < 2) {
        #pragma unroll
        for (int r = 0; r < 4; ++r) {
            const int co = g * 4 + r;
            biasF[r] = bias[co] * Berr[(size_t)b * COUT + co];
        }
    }

    // ---- per-subtile column addressing ----
    const int colA = w0 + p + g - 1;
    const int colB = colA + 16;
    const unsigned maskA = ((unsigned)colA < (unsigned)WI_ && g < 3) ? 0xffffffffu : 0u;
    const unsigned maskB = ((unsigned)colB < (unsigned)WI_ && g < 3) ? 0xffffffffu : 0u;
    const int colcA = colA < 0 ? 0 : (colA > WI_ - 1 ? WI_ - 1 : colA);
    const int colcB = colB < 0 ? 0 : (colB > WI_ - 1 ? WI_ - 1 : colB);
    const int dcol  = (colcB - colcA) * CIN;      // per-lane constant offset

    const float* __restrict__ xb = X + (size_t)b * H_ * RST;
    int voff = (rs > 0 ? rs - 1 : rs) * RST + colcA * CIN;

    float4 R0a0,R0a1,R0b0,R0b1, R1a0,R1a1,R1b0,R1b1, R2a0,R2a1,R2b0,R2b1;
    if (rs > 0) {                          // R0 <- row rs-1
        R0a0 = *(const float4*)(xb + voff);        R0a1 = *(const float4*)(xb + voff + 4);
        R0b0 = *(const float4*)(xb + voff + dcol); R0b1 = *(const float4*)(xb + voff + dcol + 4);
        voff += RST;
    } else {
        R0a0 = make_float4(0.f,0.f,0.f,0.f); R0a1 = R0a0; R0b0 = R0a0; R0b1 = R0a0;
    }
    R1a0 = *(const float4*)(xb + voff);        R1a1 = *(const float4*)(xb + voff + 4);
    R1b0 = *(const float4*)(xb + voff + dcol); R1b1 = *(const float4*)(xb + voff + dcol + 4);
    voff += RST;
    int nextRow = rs + 1;

    float* __restrict__ ob = out + (size_t)b * H_ * OST;
    int soff = (rs * WI_ + w0 + p) * COUT + g * 4;   // subtile A; B = +16*COUT

    f4 P1a = biasF, P2a = biasF, P1b = biasF, P2b = biasF;

#define STEP(Ca0,Ca1,Cb0,Cb1, Na0,Na1,Nb0,Nb1, DS) do {                        \
    Na0 = *(const float4*)(xb + voff);                                         \
    Na1 = *(const float4*)(xb + voff + 4);                                     \
    Nb0 = *(const float4*)(xb + voff + dcol);                                  \
    Nb1 = *(const float4*)(xb + voff + dcol + 4);                              \
    { const int inc_ = (nextRow < H_ - 1) ? RST : 0; voff += inc_; ++nextRow; }\
    __builtin_amdgcn_sched_barrier(0);                                         \
    const bh8 xfa = pack_mask(Ca0, Ca1, maskA);                                \
    const bh8 xfb = pack_mask(Cb0, Cb1, maskB);                                \
    const f4 dA = __builtin_amdgcn_mfma_f32_16x16x32_bf16(Wf2, xfa, P1a, 0,0,0);\
    const f4 dB = __builtin_amdgcn_mfma_f32_16x16x32_bf16(Wf2, xfb, P1b, 0,0,0);\
    P1a = __builtin_amdgcn_mfma_f32_16x16x32_bf16(Wf1, xfa, P2a, 0,0,0);       \
    P1b = __builtin_amdgcn_mfma_f32_16x16x32_bf16(Wf1, xfb, P2b, 0,0,0);       \
    P2a = __builtin_amdgcn_mfma_f32_16x16x32_bf16(Wf0, xfa, biasF, 0,0,0);     \
    P2b = __builtin_amdgcn_mfma_f32_16x16x32_bf16(Wf0, xfb, biasF, 0,0,0);     \
    if (DS) {                                                                  \
        if (lane < 32) {                                                       \
            __builtin_nontemporal_store(dA, (f4*)(ob + soff));                 \
            __builtin_nontemporal_store(dB, (f4*)(ob + soff + 16*COUT));       \
        }                                                                      \
        soff += OST;                                                           \
    }                                                                          \
} while (0)

    // step i computes input row rs-1+i, loads row rs+1+i (clamped).
    // load target by i mod 3: 0->R2, 1->R0, 2->R1. compute: 0->R0, 1->R1, 2->R2.
    // i=0: compute rs-1 (R0), load rs+1 -> R2. no store.
    STEP(R0a0,R0a1,R0b0,R0b1, R2a0,R2a1,R2b0,R2b1, 0);
    // i=1: compute rs (R1), load rs+2 -> R0. no store.
    STEP(R1a0,R1a1,R1b0,R1b1, R0a0,R0a1,R0b0,R0b1, 0);

    // i=2..31: compute rs+1..rs+30, store out rs..rs+29
    #pragma unroll 1
    for (int it = 0; it < 10; ++it) {
        STEP(R2a0,R2a1,R2b0,R2b1, R1a0,R1a1,R1b0,R1b1, 1);
        STEP(R0a0,R0a1,R0b0,R0b1, R2a0,R2a1,R2b0,R2b1, 1);
        STEP(R1a0,R1a1,R1b0,R1b1, R0a0,R0a1,R0b0,R0b1, 1);
    }
    // i=32: compute rs+31 (R2), store out rs+30; loads -> R1 (unused row rs+33 clamp)
    STEP(R2a0,R2a1,R2b0,R2b1, R1a0,R1a1,R1b0,R1b1, 1);

    // out row rs+31: kh=2 term from input row rs+32 (loaded at i=31 into R0)
    if (rs + SS < H_) {
        const bh8 xfa = pack_mask(R0a0, R0a1, maskA);
        const bh8 xfb = pack_mask(R0b0, R0b1, maskB);
        P1a = __builtin_amdgcn_mfma_f32_16x16x32_bf16(Wf2, xfa, P1a, 0, 0, 0);
        P1b = __builtin_amdgcn_mfma_f32_16x16x32_bf16(Wf2, xfb, P1b, 0, 0, 0);
    }
    if (lane < 32) {
        __builtin_nontemporal_store(P1a, (f4*)(ob + soff));
        __builtin_nontemporal_store(P1b, (f4*)(ob + soff + 16*COUT));
    }

#undef STEP
}

extern "C" void kernel_launch(void* const* d_in, const int* in_sizes, int n_in,
                              void* d_out, int out_size, void* d_ws, size_t ws_size,
                              hipStream_t stream) {
    const float* X    = (const float*)d_in[0];
    const float* Wt   = (const float*)d_in[1];
    const float* bias = (const float*)d_in[2];
    const float* Werr = (const float*)d_in[3];
    const float* Berr = (const float*)d_in[4];
    float* out = (float*)d_out;

    dim3 grid(WI_ / 128, H_ / SS, B_);    // (2, 8, 128) = 2048 blocks
    conv_mfma_kernel<<<grid, 256, 0, stream>>>(X, Wt, bias, Werr, Berr, out);
}

// Round 13
// 94.852 us; speedup vs baseline: 1.0290x; 1.0290x over previous
//
#include <hip/hip_runtime.h>
#include <hip/hip_bf16.h>

#define B_    128
#define H_    256
#define WI_   256
#define CIN   8
#define COUT  8
#define SS    32
#define RST   (WI_*CIN)     // 2048 f32 per input row
#define OST   (WI_*COUT)    // 2048 f32 per output row

typedef __attribute__((ext_vector_type(8))) short bh8;   // 8 bf16 (MFMA A/B frag)
typedef __attribute__((ext_vector_type(4))) float f4;    // MFMA C/D frag

static __device__ __forceinline__ unsigned short f2bf(float f) {
    union { __hip_bfloat16 h; unsigned short u; } c;
    c.h = __float2bfloat16(f);
    return c.u;
}

static __device__ __forceinline__ bh8 pack_mask(float4 lo, float4 hi, unsigned m) {
    union { bh8 v; unsigned short u[8]; unsigned w[4]; } r;
    r.u[0]=f2bf(lo.x); r.u[1]=f2bf(lo.y); r.u[2]=f2bf(lo.z); r.u[3]=f2bf(lo.w);
    r.u[4]=f2bf(hi.x); r.u[5]=f2bf(hi.y); r.u[6]=f2bf(hi.z); r.u[7]=f2bf(hi.w);
    r.w[0]&=m; r.w[1]&=m; r.w[2]&=m; r.w[3]&=m;
    return r.v;
}

// async DMA global->LDS, 16 B per lane (queue-held MLP, no VGPR cost)
static __device__ __forceinline__ void gl_lds16(const float* g, float* l) {
    __builtin_amdgcn_global_load_lds(
        (const __attribute__((address_space(1))) void*)g,
        (__attribute__((address_space(3))) void*)l, 16, 0, 0);
}

// Block = one sample x 32-row strip x full 256-col row.
// LDS ring: 4 slabs x 8KB (one X row each). Each wave stages its 2KB quarter
// of row r+3 (2x global_load_lds) while computing row r from LDS.
// Counted vmcnt (never 0) keeps 3 slabs of DMA permanently in flight.
// Wave = 4 x 16-col MFMA subtiles; D = Wfrag x Xfrag (dense f4 NT stores,
// deferred one step so the vmcnt ledger is uniform).
__global__ __launch_bounds__(256, 4)
void conv_mfma_kernel(const float* __restrict__ X,
                      const float* __restrict__ Wt,
                      const float* __restrict__ bias,
                      const float* __restrict__ Werr,
                      const float* __restrict__ Berr,
                      float* __restrict__ out)
{
    __shared__ float xs[4][RST];          // 32 KB row ring
    __shared__ float wlds[576];           // noisy weights [khkw][cout][cin]

    const int tid = threadIdx.x;
    const int b   = blockIdx.y;
    const int rs  = blockIdx.x * SS;

    {
        const float* we = Werr + (size_t)b * 576;
        for (int i = tid; i < 576; i += 256) {
            const int khkw = i >> 6, ci = (i >> 3) & 7, co = i & 7;
            wlds[(khkw * 8 + co) * 8 + ci] = Wt[i] * we[i];
        }
    }

    const int lane = tid & 63, wid = tid >> 6;
    const int p  = lane & 15;
    const int g  = lane >> 4;

    // bias BEFORE __syncthreads so its vm-ops drain with the sync (clean ledger)
    f4 biasF = {0.f, 0.f, 0.f, 0.f};
    if (g < 2) {
        #pragma unroll
        for (int r = 0; r < 4; ++r) {
            const int co = g * 4 + r;
            biasF[r] = bias[co] * Berr[(size_t)b * COUT + co];
        }
    }
    __syncthreads();                      // drains vmcnt(0): ledger starts clean

    // ---- weight fragments (LDS reads only -> lgkmcnt, not vmcnt) ----
    bh8 Wf0, Wf1, Wf2;
    {
        const float4 z4 = make_float4(0.f, 0.f, 0.f, 0.f);
        #pragma unroll
        for (int kh = 0; kh < 3; ++kh) {
            float4 lo = z4, hi = z4;
            if (p < 8 && g < 3) {
                const float* ptr = &wlds[((kh * 3 + g) * 8 + p) * 8];
                lo = *(const float4*)ptr;
                hi = *(const float4*)(ptr + 4);
            }
            const bh8 f = pack_mask(lo, hi, 0xffffffffu);
            if (kh == 0) Wf0 = f; else if (kh == 1) Wf1 = f; else Wf2 = f;
        }
    }

    // ---- per-subtile column constants (s = 0..3, 16 cols each) ----
    const float* __restrict__ xb = X   + (size_t)b * H_ * RST;
    float*       __restrict__ ob = out + (size_t)b * H_ * OST;
    const int stageBase = wid * 512;      // this wave's quarter (floats)

#define COLS(S, CO, MK)                                                        \
    const int col##S = wid * 64 + (S) * 16 + p + g - 1;                        \
    const unsigned MK = ((unsigned)col##S < (unsigned)WI_ && g < 3)            \
                            ? 0xffffffffu : 0u;                                \
    const int CO = (col##S < 0 ? 0 : (col##S > WI_-1 ? WI_-1 : col##S)) * CIN
    COLS(0, coff0, mask0);
    COLS(1, coff1, mask1);
    COLS(2, coff2, mask2);
    COLS(3, coff3, mask3);
#undef COLS

    // ---- prologue: stage rows rs-1, rs, rs+1 into slots 0,1,2 ----
#define STAGE_ROW(ROW, SLOT) do {                                              \
    const float* gs_ = xb + (size_t)(ROW) * RST + stageBase + lane * 4;        \
    gl_lds16(gs_,       &xs[SLOT][stageBase]);                                 \
    gl_lds16(gs_ + 256, &xs[SLOT][stageBase + 256]);                           \
} while (0)

    STAGE_ROW((rs > 0 ? rs - 1 : 0), 0);
    STAGE_ROW(rs,     1);
    STAGE_ROW(rs + 1, 2);
    int srow = rs + 2;                    // next row to stage

    int soff = (rs * WI_ + wid * 64 + p) * COUT + g * 4;   // first store: out rs
    unsigned rmask = (rs > 0) ? 0xffffffffu : 0u;          // step-0 row mask

    f4 P1_0 = biasF, P2_0 = biasF, dnp_0;
    f4 P1_1 = biasF, P2_1 = biasF, dnp_1;
    f4 P1_2 = biasF, P2_2 = biasF, dnp_2;
    f4 P1_3 = biasF, P2_3 = biasF, dnp_3;

#define SUB(SLOT, CO, MK, P1N, P2N, DN) do {                                   \
    const float4 lo_ = *(const float4*)&xs[SLOT][CO];                          \
    const float4 hi_ = *(const float4*)&xs[SLOT][(CO) + 4];                    \
    const bh8 xf_ = pack_mask(lo_, hi_, (MK) & rmask);                         \
    DN  = __builtin_amdgcn_mfma_f32_16x16x32_bf16(Wf2, xf_, P1N, 0,0,0);       \
    P1N = __builtin_amdgcn_mfma_f32_16x16x32_bf16(Wf1, xf_, P2N, 0,0,0);       \
    P2N = __builtin_amdgcn_mfma_f32_16x16x32_bf16(Wf0, xf_, biasF, 0,0,0);     \
} while (0)

// step order: wait(counted) -> barrier -> store prev dn -> stage row+3 -> compute
#define STEP(VM, SLOT, SP, DOSTAGE) do {                                       \
    asm volatile("s_waitcnt vmcnt(" #VM ")" ::: "memory");                     \
    __builtin_amdgcn_s_barrier();                                              \
    if (SP) {                                                                  \
        if (lane < 32) {                                                       \
            __builtin_nontemporal_store(dnp_0, (f4*)(ob + soff));              \
            __builtin_nontemporal_store(dnp_1, (f4*)(ob + soff + 128));        \
            __builtin_nontemporal_store(dnp_2, (f4*)(ob + soff + 256));        \
            __builtin_nontemporal_store(dnp_3, (f4*)(ob + soff + 384));        \
        }                                                                      \
        soff += OST;                                                           \
    }                                                                          \
    if (DOSTAGE) {                                                             \
        const int sr_ = srow < H_ ? srow : H_ - 1;                             \
        STAGE_ROW(sr_, (((SLOT) + 3) & 3));                                    \
        ++srow;                                                                \
    }                                                                          \
    __builtin_amdgcn_sched_barrier(0);                                         \
    SUB(SLOT, coff0, mask0, P1_0, P2_0, dnp_0);                                \
    SUB(SLOT, coff1, mask1, P1_1, P2_1, dnp_1);                                \
    SUB(SLOT, coff2, mask2, P1_2, P2_2, dnp_2);                                \
    SUB(SLOT, coff3, mask3, P1_3, P2_3, dnp_3);                                \
} while (0)

    // step i consumes slot i%4 (= input row rs-1+i), stages row rs+2+i.
    // vmcnt ledger (2 stage ops/step, 4 store ops/step from step 3 on):
    STEP(4, 0, 0, 1);  rmask = 0xffffffffu;   // i=0: row rs-1 (zeros if top)
    STEP(4, 1, 0, 1);                          // i=1: row rs
    STEP(4, 2, 0, 1);                          // i=2: row rs+1 -> dn = out rs
    STEP(4, 3, 1, 1);                          // i=3: store out rs
    STEP(8, 0, 1, 1);                          // i=4
    STEP(12, 1, 1, 1);                         // i=5
    STEP(12, 2, 1, 1);                         // i=6
    STEP(12, 3, 1, 1);                         // i=7
    #pragma unroll 1
    for (int it = 0; it < 6; ++it) {           // i = 8..31
        STEP(12, 0, 1, 1);
        STEP(12, 1, 1, 1);
        STEP(12, 2, 1, 1);
        STEP(12, 3, 1, 1);
    }
    STEP(12, 0, 1, 0);                         // i=32: row rs+31; store out rs+30

    // epilogue (i=33): row rs+32 sits in slot 1 (staged at step 30)
    asm volatile("s_waitcnt vmcnt(10)" ::: "memory");
    __builtin_amdgcn_s_barrier();
    if (lane < 32) {                           // store dn(32) = out rs+30... (deferred)
        __builtin_nontemporal_store(dnp_0, (f4*)(ob + soff));
        __builtin_nontemporal_store(dnp_1, (f4*)(ob + soff + 128));
        __builtin_nontemporal_store(dnp_2, (f4*)(ob + soff + 256));
        __builtin_nontemporal_store(dnp_3, (f4*)(ob + soff + 384));
    }
    soff += OST;
    __builtin_amdgcn_sched_barrier(0);
    if (rs + SS < H_) {                        // kh=2 term from row rs+32
#define EP(CO, MK, P1N) do {                                                   \
        const float4 lo_ = *(const float4*)&xs[1][CO];                         \
        const float4 hi_ = *(const float4*)&xs[1][(CO) + 4];                   \
        const bh8 xf_ = pack_mask(lo_, hi_, MK);                               \
        P1N = __builtin_amdgcn_mfma_f32_16x16x32_bf16(Wf2, xf_, P1N, 0,0,0);   \
} while (0)
        EP(coff0, mask0, P1_0);
        EP(coff1, mask1, P1_1);
        EP(coff2, mask2, P1_2);
        EP(coff3, mask3, P1_3);
#undef EP
    }
    if (lane < 32) {                           // out rs+31
        __builtin_nontemporal_store(P1_0, (f4*)(ob + soff));
        __builtin_nontemporal_store(P1_1, (f4*)(ob + soff + 128));
        __builtin_nontemporal_store(P1_2, (f4*)(ob + soff + 256));
        __builtin_nontemporal_store(P1_3, (f4*)(ob + soff + 384));
    }

#undef STEP
#undef SUB
#undef STAGE_ROW
}

extern "C" void kernel_launch(void* const* d_in, const int* in_sizes, int n_in,
                              void* d_out, int out_size, void* d_ws, size_t ws_size,
                              hipStream_t stream) {
    const float* X    = (const float*)d_in[0];
    const float* Wt   = (const float*)d_in[1];
    const float* bias = (const float*)d_in[2];
    const float* Werr = (const float*)d_in[3];
    const float* Berr = (const float*)d_in[4];
    float* out = (float*)d_out;

    dim3 grid(H_ / SS, B_);               // (8, 128) = 1024 blocks, 4/CU
    conv_mfma_kernel<<<grid, 256, 0, stream>>>(X, Wt, bias, Werr, Berr, out);
}